// Round 4
// baseline (485.956 us; speedup 1.0000x reference)
//
#include <hip/hip_runtime.h>
#include <math.h>

// ExpertGating: g = x @ gate_w^T + gate_b (16384x4096 @ 4096x64), top-8 desc
// (tie -> lowest idx), softmax. out: [0,131072) weights, [131072,262144) idx-as-float.
//
// R6 (resubmit after infra failure): channel-de-aliasing stagger.
//   R5 counters: x-delivery pinned at ~1.15 TB/s with VALU 9% / MFMA 4% ->
//   hard wall for the access pattern. Theory: rows are 16 KB apart; all
//   blocks read the SAME 1 KB column-window at the same time -> all requests
//   share addr bits [0..13] -> alias onto a small subset of HBM channels /
//   L3 banks (~1/10 of parallelism ~ 630 GB/s HBM, as measured).
//   Fix: block b walks chunks in order (ch + (b&15)) & 15 -> at any instant
//   the grid covers all 16 column-windows = full 16 KB period -> all banks.
//   Chunk-order permutation only changes fp32 accumulation order (safe).
//   Also: acc0/acc1 MFMA interleave to break dependent-MFMA chains.
//   Everything else = R5 (1 KB bursts, LDS dbuf bf16 hi/lo planes, swizzle,
//   pre-split B, 3 MFMA passes, MARGIN + fp64 fallback, butterfly top-9).

#define NT 16384
#define HID 4096
#define NE 64
#define TOPK 8
#define BT 32          // tokens per block
#define CK 256         // K-chunk (floats): 1 KB burst per row-visit
#define NCH (HID / CK) // 16
#define LG_S 65
#define MARGIN 2.5e-4f

typedef __attribute__((ext_vector_type(8))) short bf16x8;
typedef __attribute__((ext_vector_type(4))) float f32x4;

union BF8 { unsigned int u[4]; bf16x8 v; };

__device__ __forceinline__ unsigned int hi_pack(float a, float b) {
    return __builtin_amdgcn_perm(__float_as_uint(b), __float_as_uint(a), 0x07060302u);
}
__device__ __forceinline__ float lo_of(float f) {
    return f - __uint_as_float(__float_as_uint(f) & 0xFFFF0000u);
}
__device__ __forceinline__ bf16x8 pack_hi8(float4 a, float4 b) {
    BF8 r;
    r.u[0] = hi_pack(a.x, a.y);
    r.u[1] = hi_pack(a.z, a.w);
    r.u[2] = hi_pack(b.x, b.y);
    r.u[3] = hi_pack(b.z, b.w);
    return r.v;
}
__device__ __forceinline__ bf16x8 pack_lo8(float4 a, float4 b) {
    BF8 r;
    r.u[0] = hi_pack(lo_of(a.x), lo_of(a.y));
    r.u[1] = hi_pack(lo_of(a.z), lo_of(a.w));
    r.u[2] = hi_pack(lo_of(b.x), lo_of(b.y));
    r.u[3] = hi_pack(lo_of(b.z), lo_of(b.w));
    return r.v;
}

// ---- pre-split gate_w (64x4096 fp32) into bf16 hi/lo planes in workspace
__global__ __launch_bounds__(256)
void presplit_kernel(const float* __restrict__ gw,
                     unsigned short* __restrict__ whi,
                     unsigned short* __restrict__ wlo) {
    int i = (blockIdx.x * 256 + threadIdx.x) * 4;
    float4 v = *(const float4*)(gw + i);
    ushort4 hi = make_ushort4((unsigned short)(__float_as_uint(v.x) >> 16),
                              (unsigned short)(__float_as_uint(v.y) >> 16),
                              (unsigned short)(__float_as_uint(v.z) >> 16),
                              (unsigned short)(__float_as_uint(v.w) >> 16));
    ushort4 lo = make_ushort4((unsigned short)(__float_as_uint(lo_of(v.x)) >> 16),
                              (unsigned short)(__float_as_uint(lo_of(v.y)) >> 16),
                              (unsigned short)(__float_as_uint(lo_of(v.z)) >> 16),
                              (unsigned short)(__float_as_uint(lo_of(v.w)) >> 16));
    *(ushort4*)(whi + i) = hi;
    *(ushort4*)(wlo + i) = lo;
}

__device__ __forceinline__ void split_store(float4 v, unsigned short* ph,
                                            unsigned short* pl) {
    uint u0 = __float_as_uint(v.x), u1 = __float_as_uint(v.y);
    uint u2 = __float_as_uint(v.z), u3 = __float_as_uint(v.w);
    ushort4 hi = make_ushort4(u0 >> 16, u1 >> 16, u2 >> 16, u3 >> 16);
    ushort4 lo = make_ushort4(__float_as_uint(lo_of(v.x)) >> 16,
                              __float_as_uint(lo_of(v.y)) >> 16,
                              __float_as_uint(lo_of(v.z)) >> 16,
                              __float_as_uint(lo_of(v.w)) >> 16);
    *(ushort4*)ph = hi;
    *(ushort4*)pl = lo;
}

// PS = true: B pre-split in workspace. PS = false: convert B from fp32 inline.
template <bool PS>
__global__ __launch_bounds__(256, 2)
void gating_kernel(const float* __restrict__ x,
                   const float* __restrict__ gw,
                   const unsigned short* __restrict__ whi,
                   const unsigned short* __restrict__ wlo,
                   const float* __restrict__ gb,
                   float* __restrict__ out) {
    __shared__ __align__(16) unsigned short sxh[2][BT * CK];  // 16 KB each
    __shared__ __align__(16) unsigned short sxl[2][BT * CK];
    __shared__ float lg[BT * LG_S];
    __shared__ float thr9s[BT];
    __shared__ int flags[BT], flist[BT], fcnt;

    const int tid  = threadIdx.x;
    const int ln   = tid & 63;
    const int wv   = __builtin_amdgcn_readfirstlane(tid >> 6);  // 0..3
    const int tok0 = blockIdx.x * BT;
    const int ph   = blockIdx.x & (NCH - 1);   // chunk-phase stagger
    const int eb   = wv * 16;          // wave's 16 experts
    const int mr   = ln & 15;
    const int q    = ln >> 4;

    // stage coords: wave j-th load covers one full 1 KB row-chunk contiguously
    const int srow = wv;               // row = 4*j + srow
    const int scol = ln;               // float4 column within chunk (0..63)

    const float* a_base = x + (size_t)tok0 * HID;

    const unsigned short* hp = whi + (size_t)(eb + mr) * HID + q * 8;
    const unsigned short* lp = wlo + (size_t)(eb + mr) * HID + q * 8;
    const float*          bp = gw  + (size_t)(eb + mr) * HID + q * 8;

    f32x4 acc0 = {0.f, 0.f, 0.f, 0.f};
    f32x4 acc1 = {0.f, 0.f, 0.f, 0.f};

    float4 px[8];
    // ---- prologue: load actual chunk `ph` (1 KB contiguous per row-visit)
#pragma unroll
    for (int j = 0; j < 8; j++)
        px[j] = *(const float4*)(a_base + (size_t)(4 * j + srow) * HID + ph * CK + scol * 4);

    bf16x8 pbh, pbl;
    {
        const int ks0 = ph * 8;        // first k-step of first actual chunk
        if constexpr (PS) {
            pbh = *(const bf16x8*)(hp + ks0 * 32);
            pbl = *(const bf16x8*)(lp + ks0 * 32);
        } else {
            float4 b0 = *(const float4*)(bp + ks0 * 32);
            float4 b1 = *(const float4*)(bp + ks0 * 32 + 4);
            pbh = pack_hi8(b0, b1);
            pbl = pack_lo8(b0, b1);
        }
    }

    // convert + write chunk -> buf 0 (swizzled: ushort idx ^= (row&7)<<3)
#pragma unroll
    for (int j = 0; j < 8; j++) {
        int r  = 4 * j + srow;
        int ci = r * CK + ((scol * 4) ^ ((r & 7) << 3));
        split_store(px[j], &sxh[0][ci], &sxl[0][ci]);
    }
    __syncthreads();

    for (int ch = 0; ch < NCH; ++ch) {
        const int cb  = ch & 1;
        const int ca  = (ch + ph) & (NCH - 1);      // chunk now in LDS buf cb
        const int can = (ch + 1 + ph) & (NCH - 1);  // next chunk to stage
        // ---- issue next-chunk loads (in flight across the compute phase)
        if (ch + 1 < NCH) {
            const int k0 = can * CK;
#pragma unroll
            for (int j = 0; j < 8; j++)
                px[j] = *(const float4*)(a_base + (size_t)(4 * j + srow) * HID + k0 + scol * 4);
        }
        // ---- compute 8 k-steps from buf cb
        const unsigned short* bufh = &sxh[cb][0];
        const unsigned short* bufl = &sxl[cb][0];
        const int sw   = (mr & 7) << 3;
        const int ca8  = ca * 8;
        const int can8 = can * 8;
#pragma unroll
        for (int s = 0; s < 8; ++s) {
            bf16x8 bh = pbh, bl = pbl;
            // distance-1 B prefetch along the staggered k-step sequence
            const int nk = (s < 7) ? (ca8 + s + 1) : can8;  // ch==15: wraps, harmless
            if constexpr (PS) {
                pbh = *(const bf16x8*)(hp + nk * 32);
                pbl = *(const bf16x8*)(lp + nk * 32);
            } else {
                float4 b0 = *(const float4*)(bp + nk * 32);
                float4 b1 = *(const float4*)(bp + nk * 32 + 4);
                pbh = pack_hi8(b0, b1);
                pbl = pack_lo8(b0, b1);
            }
            const int c0 = (s * 32 + q * 8) ^ sw;
            bf16x8 a0h = *(const bf16x8*)&bufh[mr * CK + c0];
            bf16x8 a0l = *(const bf16x8*)&bufl[mr * CK + c0];
            bf16x8 a1h = *(const bf16x8*)&bufh[(16 + mr) * CK + c0];
            bf16x8 a1l = *(const bf16x8*)&bufl[(16 + mr) * CK + c0];
            // interleave acc0/acc1 to break dependent-MFMA chains
            acc0 = __builtin_amdgcn_mfma_f32_16x16x32_bf16(a0h, bh, acc0, 0, 0, 0);
            acc1 = __builtin_amdgcn_mfma_f32_16x16x32_bf16(a1h, bh, acc1, 0, 0, 0);
            acc0 = __builtin_amdgcn_mfma_f32_16x16x32_bf16(a0h, bl, acc0, 0, 0, 0);
            acc1 = __builtin_amdgcn_mfma_f32_16x16x32_bf16(a1h, bl, acc1, 0, 0, 0);
            acc0 = __builtin_amdgcn_mfma_f32_16x16x32_bf16(a0l, bh, acc0, 0, 0, 0);
            acc1 = __builtin_amdgcn_mfma_f32_16x16x32_bf16(a1l, bh, acc1, 0, 0, 0);
        }
        // ---- convert + write next chunk -> other buffer
        if (ch + 1 < NCH) {
            const int nb = cb ^ 1;
#pragma unroll
            for (int j = 0; j < 8; j++) {
                int r  = 4 * j + srow;
                int ci = r * CK + ((scol * 4) ^ ((r & 7) << 3));
                split_store(px[j], &sxh[nb][ci], &sxl[nb][ci]);
            }
        }
        __syncthreads();
    }

    // ---- epilogue: C/D layout row=(ln>>4)*4+reg (token), col=ln&15 (expert)
    {
        const int e0 = eb + mr;
        const float bb = gb[e0];
#pragma unroll
        for (int i = 0; i < 4; ++i) {
            lg[(q * 4 + i) * LG_S + e0]      = acc0[i] + bb;
            lg[(16 + q * 4 + i) * LG_S + e0] = acc1[i] + bb;
        }
    }
    if (tid == 0) fcnt = 0;
    __syncthreads();

    // ---- wave-parallel top-9: 16 lanes per token, 2 passes of 16 tokens
#pragma unroll
    for (int p = 0; p < 2; ++p) {
        const int t = p * 16 + wv * 4 + q;
        float v0 = lg[t * LG_S + mr * 4 + 0];
        float v1 = lg[t * LG_S + mr * 4 + 1];
        float v2 = lg[t * LG_S + mr * 4 + 2];
        float v3 = lg[t * LG_S + mr * 4 + 3];
        float vals9[9];
        int idx9[9];
#pragma unroll
        for (int kk = 0; kk < 9; ++kk) {
            float bv = v0; int bj = 0;
            if (v1 > bv) { bv = v1; bj = 1; }
            if (v2 > bv) { bv = v2; bj = 2; }
            if (v3 > bv) { bv = v3; bj = 3; }
            int be = (mr << 2) | bj;
#pragma unroll
            for (int off = 1; off <= 8; off <<= 1) {
                float ov = __shfl_xor(bv, off);
                int   oe = __shfl_xor(be, off);
                if (ov > bv || (ov == bv && oe < be)) { bv = ov; be = oe; }
            }
            vals9[kk] = bv; idx9[kk] = be;
            if (kk < 8 && (be >> 2) == mr) {
                int j = be & 3;
                v0 = (j == 0) ? -1e30f : v0;
                v1 = (j == 1) ? -1e30f : v1;
                v2 = (j == 2) ? -1e30f : v2;
                v3 = (j == 3) ? -1e30f : v3;
            }
        }
        if (mr == 0) {
            float mg = 1e30f;
#pragma unroll
            for (int kk = 0; kk < 8; kk++) {
                float gp = vals9[kk] - vals9[kk + 1];
                mg = (gp < mg) ? gp : mg;
            }
            int fl = (mg < MARGIN) ? 1 : 0;
            flags[t] = fl;
            thr9s[t] = vals9[8];
            if (!fl) {
                float mx = vals9[0], ex[TOPK], s = 0.f;
#pragma unroll
                for (int k = 0; k < TOPK; k++) { ex[k] = expf(vals9[k] - mx); s += ex[k]; }
                float inv = 1.0f / s;
                int gt = tok0 + t;
#pragma unroll
                for (int k = 0; k < TOPK; k++) {
                    out[gt * TOPK + k] = ex[k] * inv;
                    out[NT * TOPK + gt * TOPK + k] = (float)idx9[k];
                }
            }
        }
    }
    __syncthreads();

    if (tid == 0) {
        int n = 0;
        for (int tt = 0; tt < BT; tt++) if (flags[tt]) flist[n++] = tt;
        fcnt = n;
    }
    __syncthreads();

    // ---- fp64 fallback: one wave per flagged token, candidate experts only
    for (int i2 = wv; i2 < fcnt; i2 += 4) {
        int tt = flist[i2];
        bool active = lg[tt * LG_S + ln] >= thr9s[tt] - MARGIN;
        double p0 = 0., p1 = 0., p2 = 0., p3 = 0.;
        if (active) {
            const float* xr = x + (size_t)(tok0 + tt) * HID;
            const float* wr = gw + (size_t)ln * HID;
#pragma unroll 4
            for (int k = 0; k < HID; k += 4) {
                float4 a = *(const float4*)(xr + k);
                float4 b = *(const float4*)(wr + k);
                p0 = fma((double)a.x, (double)b.x, p0);
                p1 = fma((double)a.y, (double)b.y, p1);
                p2 = fma((double)a.z, (double)b.z, p2);
                p3 = fma((double)a.w, (double)b.w, p3);
            }
        }
        double base = active ? ((p0 + p1) + (p2 + p3) + (double)gb[ln]) : -1e18;
        double mv[TOPK];
        int mi[TOPK];
#pragma unroll
        for (int k = 0; k < TOPK; k++) {
            double v = base;
            int ii = ln;
#pragma unroll
            for (int off = 32; off >= 1; off >>= 1) {
                double ov = __shfl_xor(v, off);
                int oi = __shfl_xor(ii, off);
                if (ov > v || (ov == v && oi < ii)) { v = ov; ii = oi; }
            }
            mv[k] = v;
            mi[k] = ii;
            if (ln == ii) base = -1e18;
        }
        if (ln == 0) {
            double mx = mv[0];
            float ex[TOPK], s = 0.f;
#pragma unroll
            for (int k = 0; k < TOPK; k++) { ex[k] = expf((float)(mv[k] - mx)); s += ex[k]; }
            float inv = 1.0f / s;
            int gt = tok0 + tt;
#pragma unroll
            for (int k = 0; k < TOPK; k++) {
                out[gt * TOPK + k] = ex[k] * inv;
                out[NT * TOPK + gt * TOPK + k] = (float)mi[k];
            }
        }
    }
}

extern "C" void kernel_launch(void* const* d_in, const int* in_sizes, int n_in,
                              void* d_out, int out_size, void* d_ws, size_t ws_size,
                              hipStream_t stream) {
    const float* x  = (const float*)d_in[0];
    const float* gw = (const float*)d_in[1];
    const float* gb = (const float*)d_in[2];
    float* out = (float*)d_out;

    const size_t ws_need = (size_t)NE * HID * 4;  // hi+lo bf16 planes = 1 MiB
    bool ps = (d_ws != nullptr) && (ws_size >= ws_need);
    if (ps) {
        unsigned short* whi = (unsigned short*)d_ws;
        unsigned short* wlo = whi + (size_t)NE * HID;
        presplit_kernel<<<dim3(NE * HID / 1024), dim3(256), 0, stream>>>(gw, whi, wlo);
        gating_kernel<true><<<dim3(NT / BT), dim3(256), 0, stream>>>(x, gw, whi, wlo, gb, out);
    } else {
        gating_kernel<false><<<dim3(NT / BT), dim3(256), 0, stream>>>(x, gw, nullptr, nullptr, gb, out);
    }
}